// Round 12
// baseline (232.278 us; speedup 1.0000x reference)
//
#include <hip/hip_runtime.h>
#include <cstdint>
#include <cstddef>

#define NPTS 4096
#define KNN  16
#define INV_DEG (1.0f / 17.0f)
#define CAP  48   // knn per-point candidate buffer (entries [48..64) = slot staging)

typedef unsigned long long u64;
typedef unsigned int u32;
typedef float v2f __attribute__((ext_vector_type(2)));

// Raw keys: (f32bits(d2) << 32) | j; as f64 this is order-isomorphic to
// (d2 asc, idx asc) for finite d2 (R11, verified). Sentinels: exponent 0x7F8
// (finite huge), low32 >= 0xFFFFFFFE never collides with idx < 4096.
#define UNUSED_K 0x7F800000FFFFFFFFull
#define SELF_K   0x7F800000FFFFFFFEull

__device__ __forceinline__ double as_f64(u64 k) { return __longlong_as_double((long long)k); }
__device__ __forceinline__ int sp3(int v) { return ((v & 4) << 4) | ((v & 2) << 2) | (v & 1); }

// ---------------------------------------------------------------------------
// K0: counting-sort points by 3-bit/axis Morton cell. One block per batch.
// Order within a cell is atomic-race arbitrary — harmless: selection is an
// order-independent exact set, and AABBs are computed from the ACTUAL array.
// Clamp only affects locality, never correctness.
// ---------------------------------------------------------------------------
__global__ __launch_bounds__(512) void bin_kernel(const float* __restrict__ feats,
                                                  float4* __restrict__ sortedG) {
  __shared__ int hist[512];
  __shared__ int tmp[512];
  const int b = blockIdx.x;
  const int tid = threadIdx.x;
  const float* fb = feats + (size_t)b * NPTS * 6;
  hist[tid] = 0;
  __syncthreads();
  float px[8], py[8], pz[8];
  int pm[8];
#pragma unroll
  for (int i = 0; i < 8; ++i) {
    const int n = tid + 512 * i;
    const float* fr = fb + (size_t)n * 6;
    const float x = fr[0], y = fr[1], z = fr[2];
    int cx = (int)floorf((x + 5.f) * 0.8f);
    int cy = (int)floorf((y + 5.f) * 0.8f);
    int cz = (int)floorf((z + 5.f) * 0.8f);
    cx = cx < 0 ? 0 : (cx > 7 ? 7 : cx);
    cy = cy < 0 ? 0 : (cy > 7 ? 7 : cy);
    cz = cz < 0 ? 0 : (cz > 7 ? 7 : cz);
    const int m = sp3(cx) | (sp3(cy) << 1) | (sp3(cz) << 2);
    px[i] = x; py[i] = y; pz[i] = z; pm[i] = m;
    atomicAdd(&hist[m], 1);
  }
  __syncthreads();
  const int myc = hist[tid];
  int v = myc;
  for (int off = 1; off < 512; off <<= 1) {  // Hillis-Steele inclusive scan
    tmp[tid] = v;
    __syncthreads();
    if (tid >= off) v += tmp[tid - off];
    __syncthreads();
  }
  hist[tid] = v - myc;  // exclusive start; becomes running cursor
  __syncthreads();
#pragma unroll
  for (int i = 0; i < 8; ++i) {
    const int n = tid + 512 * i;
    const int pos = atomicAdd(&hist[pm[i]], 1);
    float4 o; o.x = px[i]; o.y = py[i]; o.z = pz[i]; o.w = (float)n;  // orig idx
    sortedG[(size_t)b * NPTS + pos] = o;
  }
}

// ---------------------------------------------------------------------------
// K0b: per-64-batch AABB of the sorted array. One wave per batch (512 blocks).
// ---------------------------------------------------------------------------
__global__ __launch_bounds__(64) void aabb_kernel(const float4* __restrict__ sortedG,
                                                  float4* __restrict__ aabbLo,
                                                  float4* __restrict__ aabbHi) {
  const int blk = blockIdx.x;
  const int lane = threadIdx.x;
  const float4 c = sortedG[(size_t)blk * 64 + lane];
  float lx = c.x, ly = c.y, lz = c.z, hx = c.x, hy = c.y, hz = c.z;
#pragma unroll
  for (int m = 1; m < 64; m <<= 1) {
    lx = fminf(lx, __shfl_xor(lx, m, 64));
    ly = fminf(ly, __shfl_xor(ly, m, 64));
    lz = fminf(lz, __shfl_xor(lz, m, 64));
    hx = fmaxf(hx, __shfl_xor(hx, m, 64));
    hy = fmaxf(hy, __shfl_xor(hy, m, 64));
    hz = fmaxf(hz, __shfl_xor(hz, m, 64));
  }
  if (lane == 0) {
    float4 lo; lo.x = lx; lo.y = ly; lo.z = lz; lo.w = 0.f;
    float4 hi; hi.x = hx; hi.y = hy; hi.z = hz; hi.w = 0.f;
    aabbLo[blk] = lo;
    aabbHi[blk] = hi;
  }
}

// ---------------------------------------------------------------------------
// K1: exact KNN (top-16 smallest d2, tie -> lower index) + fused enc1.
// Ledger: (R3) no min-waves hint; (R4) flush = LDS rank-select, not shfl
// bitonic; (R5/R6) LDS residency cliffs; (R7/R8) cover all 32768 pts;
// (R10) smaller tiles bought nothing; (R11) f64-cmp neutral -> flush is
// LDS/issue-bound, scan is ballot-machinery-bound => R12 goes algorithmic:
// Morton-sorted candidates, outward scan from own batch, two-level AABB
// pruning with conservative margin (prune iff lb > tau*1.0001+1e-5; f32
// cancellation error ~7e-6 << margin). Waves take sorted-ADJACENT point
// pairs so their joint wave-box is tiny.
// ---------------------------------------------------------------------------
__global__ __launch_bounds__(512) void knn_kernel(const float4* __restrict__ sortedG,
                                                  const float4* __restrict__ aabbLo,
                                                  const float4* __restrict__ aabbHi,
                                                  const float* __restrict__ feats,
                                                  const float* __restrict__ W1,
                                                  const float* __restrict__ b1,
                                                  int* __restrict__ nbr,
                                                  float* __restrict__ x1) {
#pragma clang fp contract(off)
  __shared__ float4 slo[64], shi[64];  // 2 KB batch AABBs
  __shared__ float4 tlo[8], thi[8];    // 256 B tile AABBs
  __shared__ u64 sbuf[8][2][64];       // 8 KB

  const int b = blockIdx.x >> 8;
  const int pbase = (blockIdx.x & 255) * 16;  // sorted-position base
  const float4* sb_ = sortedG + (size_t)b * NPTS;
  const float* fb = feats + (size_t)b * NPTS * 6;
  const int tid = threadIdx.x;
  const int wave = tid >> 6;
  const int lane = tid & 63;

  if (tid < 64) slo[tid] = aabbLo[b * 64 + tid];
  else if (tid < 128) shi[tid - 64] = aabbHi[b * 64 + tid - 64];
  __syncthreads();
  if (tid < 8) {
    float4 lo = slo[tid * 8], hi = shi[tid * 8];
#pragma unroll
    for (int i = 1; i < 8; ++i) {
      const float4 l2 = slo[tid * 8 + i], h2 = shi[tid * 8 + i];
      lo.x = fminf(lo.x, l2.x); lo.y = fminf(lo.y, l2.y); lo.z = fminf(lo.z, l2.z);
      hi.x = fmaxf(hi.x, h2.x); hi.y = fmaxf(hi.y, h2.y); hi.z = fmaxf(hi.z, h2.z);
    }
    tlo[tid] = lo; thi[tid] = hi;
  }
  __syncthreads();

  int ip[2];
  float xi[2], yi[2], zi[2], sqi[2], tau[2];
  u64 slot[2];
  int cnt[2];
#pragma unroll
  for (int p = 0; p < 2; ++p) {
    const int s = pbase + wave * 2 + p;  // sorted position
    const float4 own = sb_[s];
    xi[p] = own.x; yi[p] = own.y; zi[p] = own.z;
    ip[p] = (int)own.w;  // ORIGINAL index (output identity)
    sqi[p] = __fadd_rn(__fadd_rn(__fmul_rn(xi[p], xi[p]), __fmul_rn(yi[p], yi[p])),
                       __fmul_rn(zi[p], zi[p]));
    tau[p] = __uint_as_float(0x7f800000u);  // +inf
    slot[p] = UNUSED_K;
    cnt[p] = 0;
  }
  const int ob = (pbase + wave * 2) >> 6;  // own batch (even s: never straddles)
  const int ot = ob >> 3, obr = ob & 7;
  // wave-box over the 2 (Morton-adjacent) points
  const float wxl = fminf(xi[0], xi[1]), wxh = fmaxf(xi[0], xi[1]);
  const float wyl = fminf(yi[0], yi[1]), wyh = fmaxf(yi[0], yi[1]);
  const float wzl = fminf(zi[0], zi[1]), wzh = fmaxf(zi[0], zi[1]);

  // LDS rank-select merge of {<=48 buffered} U {16 slots} (R11 verbatim).
  auto flush = [&](int p) {
    u64* wb = &sbuf[wave][p][0];
    if (lane >= cnt[p] && lane < CAP) wb[lane] = UNUSED_K;
    if (lane < KNN) wb[CAP + lane] = slot[p];
    u64 myk = wb[lane];
    if ((u32)myk == (u32)ip[p]) {  // neutralize self
      myk = SELF_K;
      wb[lane] = SELF_K;
    }
    const double dm = as_f64(myk);
    int rank = 0;
#pragma unroll
    for (int m = 0; m < 64; m += 4) {
      const double k0 = as_f64(wb[m]), k1 = as_f64(wb[m + 1]);
      const double k2 = as_f64(wb[m + 2]), k3 = as_f64(wb[m + 3]);
      rank += (int)(k0 < dm) + (int)(k1 < dm) + (int)(k2 < dm) + (int)(k3 < dm);
    }
    if (rank < KNN) wb[rank] = myk;
    u64 s15 = wb[15];
    if (lane < KNN) slot[p] = wb[lane];
    tau[p] = __uint_as_float((u32)(s15 >> 32));
    cnt[p] = 0;
  };

  auto boxLB = [&](float4 lo, float4 hi) -> float {
    const float dx = fmaxf(fmaxf(lo.x - wxh, wxl - hi.x), 0.f);
    const float dy = fmaxf(fmaxf(lo.y - wyh, wyl - hi.y), 0.f);
    const float dz = fmaxf(fmaxf(lo.z - wzh, wzl - hi.z), 0.f);
    return dx * dx + dy * dy + dz * dz;
  };

  auto scanTile = [&](int t) {
    {
      const float lim = __fmaf_rn(fmaxf(tau[0], tau[1]), 1.0001f, 1e-5f);
      if (boxLB(tlo[t], thi[t]) > lim) return;  // wave-uniform branch
    }
#pragma unroll 1
    for (int bt = 0; bt < 8; ++bt) {
      const int jb = t * 8 + ((t == ot) ? ((obr + bt) & 7) : bt);  // own batch first
      const float lim = __fmaf_rn(fmaxf(tau[0], tau[1]), 1.0001f, 1e-5f);
      if (boxLB(slo[jb], shi[jb]) > lim) continue;
      // ---- full batch scan (R11 body; candidate identity from .w) ----
      const float4 c = sb_[jb * 64 + lane];
      const float sq = __fadd_rn(__fadd_rn(__fmul_rn(c.x, c.x), __fmul_rn(c.y, c.y)),
                                 __fmul_rn(c.z, c.z));
      const u32 cj = (u32)(int)c.w;
      const v2f cx2 = {c.x, c.x}, cy2 = {c.y, c.y}, cz2 = {c.z, c.z}, sq2 = {sq, sq};
      v2f X = {xi[0], xi[1]};
      v2f Y = {yi[0], yi[1]};
      v2f Z = {zi[0], zi[1]};
      v2f SQ = {sqi[0], sqi[1]};
      v2f dot = X * cx2;
      dot = __builtin_elementwise_fma(Y, cy2, dot);
      dot = __builtin_elementwise_fma(Z, cz2, dot);
      v2f two = {2.0f, 2.0f};
      v2f d2v = (SQ + sq2) - two * dot;  // contract(off): rn each op
      float d2s[2] = {d2v.x, d2v.y};
#pragma unroll
      for (int p = 0; p < 2; ++p) {
        const bool pred = d2s[p] <= tau[p];
        const u64 bal = __ballot(pred);
        if (bal) {
          const int npass = __popcll(bal);
          if (cnt[p] + npass > CAP) flush(p);
          const int pos = cnt[p] + (int)__builtin_amdgcn_mbcnt_hi(
                                        (u32)(bal >> 32),
                                        __builtin_amdgcn_mbcnt_lo((u32)bal, 0));
          const u64 key = ((u64)__float_as_uint(d2s[p]) << 32) | cj;
          if (npass <= CAP) {
            if (pred) sbuf[wave][p][pos] = key;
            cnt[p] += npass;
          } else {  // npass in (48,64]: own-batch bootstrap + pathological ties
            if (pred && pos < CAP) sbuf[wave][p][pos] = key;
            cnt[p] = CAP;
            flush(p);
            if (pred && pos >= CAP) sbuf[wave][p][pos - CAP] = key;
            cnt[p] = npass - CAP;
          }
        }
      }
    }
  };

  for (int t = ot; t >= 0; --t) scanTile(t);
  for (int t = ot + 1; t < 8; ++t) scanTile(t);

#pragma unroll
  for (int p = 0; p < 2; ++p) flush(p);  // final merge -> slots hold winners

  // ---- fused enc1: x1[n] = relu(((Σ_{nbr ∪ self} feats) @ W1)*inv_deg + b1)
  float* fsc = (float*)&sbuf[wave][0][0];  // wave-private scratch
  float w1r[6];
#pragma unroll
  for (int k = 0; k < 6; ++k) w1r[k] = W1[k * 64 + lane];
  const float b1r = b1[lane];

#pragma unroll
  for (int p = 0; p < 2; ++p) {
    const int n = b * NPTS + ip[p];
    const int row = (lane < KNN) ? (int)(u32)slot[p] : ip[p];
    if (lane < KNN)
      nbr[(size_t)n * KNN + lane] = row;  // for enc23's gather
    if (lane < 17) {
      const float* fr = fb + (size_t)row * 6;
      float2 r0 = *(const float2*)(fr);
      float2 r1 = *(const float2*)(fr + 2);
      float2 r2 = *(const float2*)(fr + 4);
      fsc[lane * 6 + 0] = r0.x; fsc[lane * 6 + 1] = r0.y;
      fsc[lane * 6 + 2] = r1.x; fsc[lane * 6 + 3] = r1.y;
      fsc[lane * 6 + 4] = r2.x; fsc[lane * 6 + 5] = r2.y;
    }
    __syncthreads();  // uniform: every wave runs both iterations
    if (lane < 6) {
      float s = 0.f;
#pragma unroll
      for (int t = 0; t < 17; ++t) s += fsc[t * 6 + lane];
      fsc[102 + lane] = s;
    }
    __syncthreads();
    float s = 0.f;
#pragma unroll
    for (int k = 0; k < 6; ++k) s = fmaf(fsc[102 + k], w1r[k], s);
    x1[(size_t)n * 64 + lane] = fmaxf(fmaf(s, INV_DEG, b1r), 0.f);
    __syncthreads();  // protect fsc reuse for p=1
  }
}

// ---------------------------------------------------------------------------
// T2: FUSED enc2+enc3 (R10 verbatim — best measured tail). 16 pts/block,
// grid 2048 (coverage 32768 ✓). x2 never leaves LDS.
// ---------------------------------------------------------------------------
__global__ __launch_bounds__(256) void enc23_kernel(const float* __restrict__ x1,
                                                    const int* __restrict__ nbr,
                                                    const float* __restrict__ W2,
                                                    const float* __restrict__ b2,
                                                    const float* __restrict__ Wf,
                                                    const float* __restrict__ bf,
                                                    float* __restrict__ out) {
  __shared__ float a1s[16][64];  // 4 KB
  __shared__ v2f wt[16][64];     // 8 KB streaming weight tile
  __shared__ float xs[16][128];  // 8 KB x2 tile
  const int tid = threadIdx.x;
  const int n0 = blockIdx.x * 16;
  const int gb = n0 & ~(NPTS - 1);
  const int wave = tid >> 6, lane = tid & 63;

  {
    const int p = tid >> 4, c4 = tid & 15;
    const int n = n0 + p;
    const int* nb = nbr + (size_t)n * KNN;
    float4 s = ((const float4*)(x1 + (size_t)n * 64))[c4];
#pragma unroll
    for (int t = 0; t < KNN; ++t) {
      float4 v = ((const float4*)(x1 + (size_t)(gb + nb[t]) * 64))[c4];
      s.x += v.x; s.y += v.y; s.z += v.z; s.w += v.w;
    }
    *((float4*)&a1s[p][c4 * 4]) = s;
  }

  const int p0 = wave * 4;
  const float bx = b2[lane], by = b2[lane + 64];

  v2f acc[4];
#pragma unroll
  for (int i = 0; i < 4; ++i) acc[i] = (v2f){0, 0};
  for (int kt = 0; kt < 64; kt += 16) {
    __syncthreads();
#pragma unroll
    for (int i = 0; i < 4; ++i) {
      const int e = tid + 256 * i;
      const int k = e >> 6, l = e & 63;
      v2f w;
      w.x = W2[(kt + k) * 128 + l];
      w.y = W2[(kt + k) * 128 + 64 + l];
      wt[k][l] = w;
    }
    __syncthreads();
    for (int kk = 0; kk < 16; kk += 4) {
      float4 a[4];
#pragma unroll
      for (int i = 0; i < 4; ++i) a[i] = *(const float4*)&a1s[p0 + i][kt + kk];
#pragma unroll
      for (int j = 0; j < 4; ++j) {
        const v2f w = wt[kk + j][lane];
#pragma unroll
        for (int i = 0; i < 4; ++i) {
          const float e = j == 0 ? a[i].x : j == 1 ? a[i].y : j == 2 ? a[i].z
                                                                     : a[i].w;
          v2f v = {e, e};
          acc[i] = __builtin_elementwise_fma(v, w, acc[i]);
        }
      }
    }
  }
#pragma unroll
  for (int pi = 0; pi < 4; ++pi) {
    xs[p0 + pi][lane] = fmaxf(fmaf(acc[pi].x, INV_DEG, bx), 0.f);
    xs[p0 + pi][lane + 64] = fmaxf(fmaf(acc[pi].y, INV_DEG, by), 0.f);
  }

  v2f facc[4];
#pragma unroll
  for (int i = 0; i < 4; ++i) facc[i] = (v2f){0, 0};
  for (int jt = 0; jt < 128; jt += 16) {
    __syncthreads();
#pragma unroll
    for (int i = 0; i < 4; ++i) {
      const int e = tid + 256 * i;
      const int j = e >> 6, l = e & 63;
      v2f w;
      w.x = Wf[(jt + j) * 128 + l];
      w.y = Wf[(jt + j) * 128 + 64 + l];
      wt[j][l] = w;
    }
    __syncthreads();
    for (int jj = 0; jj < 16; jj += 4) {
      float4 a[4];
#pragma unroll
      for (int i = 0; i < 4; ++i) a[i] = *(const float4*)&xs[p0 + i][jt + jj];
#pragma unroll
      for (int j2 = 0; j2 < 4; ++j2) {
        const v2f w = wt[jj + j2][lane];
#pragma unroll
        for (int i = 0; i < 4; ++i) {
          const float e = j2 == 0 ? a[i].x : j2 == 1 ? a[i].y : j2 == 2 ? a[i].z
                                                                        : a[i].w;
          v2f v = {e, e};
          facc[i] = __builtin_elementwise_fma(v, w, facc[i]);
        }
      }
    }
  }
  const float fx = bf[lane], fy = bf[lane + 64];
#pragma unroll
  for (int pi = 0; pi < 4; ++pi) {
    float* row = out + (size_t)(n0 + p0 + pi) * 128;
    row[lane] = facc[pi].x + fx;
    row[lane + 64] = facc[pi].y + fy;
  }
}

// ---------------------------------------------------------------------------
// Workspace: nbr@0 (2MB), x1@2MB (8MB), sortedG@10MB (512KB),
// aabbLo@10.5MB (8KB), aabbHi@10.5MB+8KB.
// ---------------------------------------------------------------------------
extern "C" void kernel_launch(void* const* d_in, const int* in_sizes, int n_in,
                              void* d_out, int out_size, void* d_ws, size_t ws_size,
                              hipStream_t stream) {
  const float* feats = (const float*)d_in[0];
  const float* W1 = (const float*)d_in[1];
  const float* b1 = (const float*)d_in[2];
  const float* W2 = (const float*)d_in[3];
  const float* b2 = (const float*)d_in[4];
  const float* Wf = (const float*)d_in[5];
  const float* bf = (const float*)d_in[6];
  float* out = (float*)d_out;

  char* ws = (char*)d_ws;
  int* nbr = (int*)ws;
  float* x1 = (float*)(ws + (size_t)(2 << 20));
  float4* sortedG = (float4*)(ws + (size_t)(10 << 20));
  float4* aabbLo = (float4*)(ws + (size_t)(10 << 20) + (512 << 10));
  float4* aabbHi = (float4*)(ws + (size_t)(10 << 20) + (520 << 10));

  bin_kernel<<<8, 512, 0, stream>>>(feats, sortedG);
  aabb_kernel<<<512, 64, 0, stream>>>(sortedG, aabbLo, aabbHi);
  knn_kernel<<<2048, 512, 0, stream>>>(sortedG, aabbLo, aabbHi, feats, W1, b1, nbr, x1);
  enc23_kernel<<<2048, 256, 0, stream>>>(x1, nbr, W2, b2, Wf, bf, out);
}